// Round 5
// baseline (1497.652 us; speedup 1.0000x reference)
//
#include <hip/hip_runtime.h>

typedef short v8s __attribute__((ext_vector_type(8)));   // 8 x bf16 (4 VGPR)
typedef float v4f __attribute__((ext_vector_type(4)));

__device__ __forceinline__ unsigned short f2bf(float f) {
    unsigned u = __builtin_bit_cast(unsigned, f);
    u += 0x7fffu + ((u >> 16) & 1u);               // RNE
    return (unsigned short)(u >> 16);
}
__device__ __forceinline__ unsigned pk2(float a, float b) {
    return (unsigned)f2bf(a) | ((unsigned)f2bf(b) << 16);
}
__device__ __forceinline__ v8s pack8(float4 f0, float4 f1) {
    union { unsigned u[4]; v8s v; } r;
    r.u[0] = pk2(f0.x, f0.y); r.u[1] = pk2(f0.z, f0.w);
    r.u[2] = pk2(f1.x, f1.y); r.u[3] = pk2(f1.z, f1.w);
    return r.v;
}
__device__ __forceinline__ float sigm(float x) {
    float e = __builtin_amdgcn_exp2f(-1.44269504f * x);
    return __builtin_amdgcn_rcpf(1.0f + e);
}
__device__ __forceinline__ float tanh_(float x) {
    float e = __builtin_amdgcn_exp2f(2.88539008f * x);
    return 1.0f - 2.0f * __builtin_amdgcn_rcpf(1.0f + e);
}
__device__ __forceinline__ v4f mfma(v8s a, v8s b, v4f c) {
    return __builtin_amdgcn_mfma_f32_16x16x32_bf16(a, b, c, 0, 0, 0);
}
// B-frag for Z = Xin @ W^T from f32 W: lane holds W[n][k0..k0+7] as bf16.
__device__ __forceinline__ v8s ldwf(const float* W, int rowElems, int n, int k0) {
    const float* p = W + (size_t)n * rowElems + k0;
    v8s r;
    #pragma unroll
    for (int j = 0; j < 8; ++j) r[j] = (short)f2bf(p[j]);
    return r;
}

// 1024 blocks x 256 threads; 16 batch rows per block (one 16x16 M-tile).
// 4 blocks/CU (grid/256 CUs = 4), 16 waves/CU = 4 waves/SIMD: the R4 profile
// showed occupancy grid-capped at 2 blocks/CU with VALUBusy 58% — this doubles
// latency-hiding TLP at identical total VALU work.
__global__ __launch_bounds__(256, 4) void seq2seq(
    const float* __restrict__ X,
    const float* __restrict__ bias,
    const float* __restrict__ eWih0, const float* __restrict__ eWhh0, const float* __restrict__ eb0,
    const float* __restrict__ eWih1, const float* __restrict__ eWhh1, const float* __restrict__ eb1,
    const float* __restrict__ dWih0, const float* __restrict__ dWhh0, const float* __restrict__ db0,
    const float* __restrict__ dWih1, const float* __restrict__ dWhh1, const float* __restrict__ db1,
    const float* __restrict__ rW1, const float* __restrict__ rb1,
    const float* __restrict__ rW2, const float* __restrict__ rb2,
    float* __restrict__ out)
{
    // h staging, frag-linear: [parity][kk*512 + lane*8 + j], bf16
    __shared__ __align__(16) short sh0[2][1024];
    __shared__ __align__(16) short sh1[2][1024];
    __shared__ __align__(16) short sy1[1024];

    const int tid  = threadIdx.x;
    const int lane = tid & 63;
    const int w    = tid >> 6;            // unit-group 0..3 (units 16w..16w+15)
    const int lo   = lane & 15, hi = lane >> 4;
    const int wg   = blockIdx.x;          // 16 batch rows per block

    // zero parity-1 staging (initial h = 0): shorts [1024,2048) = ints [512,1024)
    for (int i = tid; i < 512; i += 256) {
        ((int*)sh0)[512 + i] = 0;
        ((int*)sh1)[512 + i] = 0;
    }

    // staging write index for value (m = hi*4+q, u = 16w+lo):
    const int wsidx = (w >> 1) * 512 + (((2 * w) + (lo >> 3)) & 3) * 128 + hi * 32 + (lo & 7);

    // ---- encoder weights -> register B-frags (f32 -> bf16) ----
    v8s wf[4][4][2];                      // [matrix][gate g (Ntile=w+4g)][kstep]
    float bz0[4], bz1[4];
    #pragma unroll
    for (int g = 0; g < 4; ++g) {
        const int n = (w + 4 * g) * 16 + lo;       // z column (row of W)
        v8s z = {0, 0, 0, 0, 0, 0, 0, 0};
        wf[0][g][0] = (hi < 2) ? ldwf(eWih0, 16, n, (hi & 1) * 8) : z;  // K=16, zero-pad k>=16
        wf[0][g][1] = z;
        #pragma unroll
        for (int kk = 0; kk < 2; ++kk) {
            wf[1][g][kk] = ldwf(eWhh0, 64, n, kk * 32 + hi * 8);
            wf[2][g][kk] = ldwf(eWih1, 64, n, kk * 32 + hi * 8);
            wf[3][g][kk] = ldwf(eWhh1, 64, n, kk * 32 + hi * 8);
        }
        bz0[g] = eb0[g * 64 + w * 16 + lo];
        bz1[g] = eb1[g * 64 + w * 16 + lo];
    }

    float c0[4] = {0.f, 0.f, 0.f, 0.f};
    float c1[4] = {0.f, 0.f, 0.f, 0.f};
    __syncthreads();   // staging zeros visible

    const float* xb = X + (size_t)(wg * 16 + lo) * 1536 + (hi & 1) * 8;

    // ================= encoder (ONE barrier per step) =================
    for (int t = 0; t < 96; ++t) {
        const int pw = t & 1, pr = pw ^ 1;
        v4f acc[4];
        // ---- layer 0: z = x_t@Wih0^T + h0@Whh0^T + b0 ----
        #pragma unroll
        for (int g = 0; g < 4; ++g) acc[g] = (v4f){bz0[g], bz0[g], bz0[g], bz0[g]};
        {
            const float* p = xb + t * 16;
            const v8s ax = pack8(*(const float4*)p, *(const float4*)(p + 4));
            #pragma unroll
            for (int g = 0; g < 4; ++g) acc[g] = mfma(ax, wf[0][g][0], acc[g]);
        }
        #pragma unroll
        for (int kk = 0; kk < 2; ++kk) {
            const v8s ah = *(const v8s*)&sh0[pr][kk * 512 + lane * 8];
            #pragma unroll
            for (int g = 0; g < 4; ++g) acc[g] = mfma(ah, wf[1][g][kk], acc[g]);
        }
        {
            float hh[4];
            #pragma unroll
            for (int q = 0; q < 4; ++q) {
                float cc = sigm(acc[1][q]) * c0[q] + sigm(acc[0][q]) * tanh_(acc[2][q]);
                c0[q] = cc;
                hh[q] = sigm(acc[3][q]) * tanh_(cc);
            }
            #pragma unroll
            for (int qp = 0; qp < 2; ++qp) {
                unsigned pk = pk2(hh[2 * qp], hh[2 * qp + 1]);
                short* b = &sh0[pw][wsidx + qp * 16];
                b[0] = (short)pk; b[8] = (short)(pk >> 16);
            }
        }
        __syncthreads();
        // ---- layer 1: z = h0@Wih1^T + h1@Whh1^T + b1 ----
        #pragma unroll
        for (int g = 0; g < 4; ++g) acc[g] = (v4f){bz1[g], bz1[g], bz1[g], bz1[g]};
        #pragma unroll
        for (int kk = 0; kk < 2; ++kk) {
            const v8s ah = *(const v8s*)&sh0[pw][kk * 512 + lane * 8];
            const v8s bh = *(const v8s*)&sh1[pr][kk * 512 + lane * 8];
            #pragma unroll
            for (int g = 0; g < 4; ++g) {
                acc[g] = mfma(ah, wf[2][g][kk], acc[g]);
                acc[g] = mfma(bh, wf[3][g][kk], acc[g]);
            }
        }
        {
            float hh[4];
            #pragma unroll
            for (int q = 0; q < 4; ++q) {
                float cc = sigm(acc[1][q]) * c1[q] + sigm(acc[0][q]) * tanh_(acc[2][q]);
                c1[q] = cc;
                hh[q] = sigm(acc[3][q]) * tanh_(cc);
            }
            #pragma unroll
            for (int qp = 0; qp < 2; ++qp) {
                unsigned pk = pk2(hh[2 * qp], hh[2 * qp + 1]);
                short* b = &sh1[pw][wsidx + qp * 16];
                b[0] = (short)pk; b[8] = (short)(pk >> 16);
            }
        }
        // no second barrier: next l0 writes sh0[pr] (disjoint from sh0[pw]/sh1[*]
        // read in l1); cross-wave producer->consumer pairs are ordered by the
        // mid-step barrier of the following step.
    }
    __syncthreads();   // order enc t=95 l1 writes (sh1[1]) before dec s=0 reads
    // finals: h0 in sh0[1], h1 in sh1[1]

    // ---- decoder + head weights -> registers ----
    #pragma unroll
    for (int g = 0; g < 4; ++g) {
        const int n = (w + 4 * g) * 16 + lo;
        #pragma unroll
        for (int kk = 0; kk < 2; ++kk) {
            wf[0][g][kk] = ldwf(dWih0, 64, n, kk * 32 + hi * 8);
            wf[1][g][kk] = ldwf(dWhh0, 64, n, kk * 32 + hi * 8);
            wf[2][g][kk] = ldwf(dWih1, 64, n, kk * 32 + hi * 8);
            wf[3][g][kk] = ldwf(dWhh1, 64, n, kk * 32 + hi * 8);
        }
        bz0[g] = db0[g * 64 + w * 16 + lo];
        bz1[g] = db1[g * 64 + w * 16 + lo];
    }
    v8s w1f[2], w2f[2];
    #pragma unroll
    for (int kk = 0; kk < 2; ++kk) {
        w1f[kk] = ldwf(rW1, 64, w * 16 + lo, kk * 32 + hi * 8);
        w2f[kk] = ldwf(rW2, 64, lo, kk * 32 + hi * 8);
    }
    const float hb1 = rb1[w * 16 + lo];
    const float hb2 = rb2[lo];
    float lb[4];
    #pragma unroll
    for (int q = 0; q < 4; ++q) {
        lb[q] = bias[(size_t)(wg * 16 + hi * 4 + q) * 16 + lo];
        c0[q] = 0.f;
        c1[q] = 0.f;
    }

    // ================= decoder =================
    for (int s = 0; s < 24; ++s) {
        const int pw = s & 1, pr = pw ^ 1;   // s=0 reads parity 1 = encoder finals
        v4f acc[4];
        // ---- dec layer 0: x = h_t (sh1[pr]), hidden = dh0 (sh0[pr]) -> sh0[pw] ----
        #pragma unroll
        for (int g = 0; g < 4; ++g) acc[g] = (v4f){bz0[g], bz0[g], bz0[g], bz0[g]};
        #pragma unroll
        for (int kk = 0; kk < 2; ++kk) {
            const v8s ah = *(const v8s*)&sh1[pr][kk * 512 + lane * 8];
            const v8s bh = *(const v8s*)&sh0[pr][kk * 512 + lane * 8];
            #pragma unroll
            for (int g = 0; g < 4; ++g) {
                acc[g] = mfma(ah, wf[0][g][kk], acc[g]);
                acc[g] = mfma(bh, wf[1][g][kk], acc[g]);
            }
        }
        {
            float hh[4];
            #pragma unroll
            for (int q = 0; q < 4; ++q) {
                float cc = sigm(acc[1][q]) * c0[q] + sigm(acc[0][q]) * tanh_(acc[2][q]);
                c0[q] = cc;
                hh[q] = sigm(acc[3][q]) * tanh_(cc);
            }
            #pragma unroll
            for (int qp = 0; qp < 2; ++qp) {
                unsigned pk = pk2(hh[2 * qp], hh[2 * qp + 1]);
                short* b = &sh0[pw][wsidx + qp * 16];
                b[0] = (short)pk; b[8] = (short)(pk >> 16);
            }
        }
        __syncthreads();
        // ---- dec layer 1: x = sh0[pw], hidden = dh1 (sh1[pr]) -> sh1[pw] ----
        #pragma unroll
        for (int g = 0; g < 4; ++g) acc[g] = (v4f){bz1[g], bz1[g], bz1[g], bz1[g]};
        #pragma unroll
        for (int kk = 0; kk < 2; ++kk) {
            const v8s ah = *(const v8s*)&sh0[pw][kk * 512 + lane * 8];
            const v8s bh = *(const v8s*)&sh1[pr][kk * 512 + lane * 8];
            #pragma unroll
            for (int g = 0; g < 4; ++g) {
                acc[g] = mfma(ah, wf[2][g][kk], acc[g]);
                acc[g] = mfma(bh, wf[3][g][kk], acc[g]);
            }
        }
        {
            float hh[4];
            #pragma unroll
            for (int q = 0; q < 4; ++q) {
                float cc = sigm(acc[1][q]) * c1[q] + sigm(acc[0][q]) * tanh_(acc[2][q]);
                c1[q] = cc;
                hh[q] = sigm(acc[3][q]) * tanh_(cc);
            }
            #pragma unroll
            for (int qp = 0; qp < 2; ++qp) {
                unsigned pk = pk2(hh[2 * qp], hh[2 * qp + 1]);
                short* b = &sh1[pw][wsidx + qp * 16];
                b[0] = (short)pk; b[8] = (short)(pk >> 16);
            }
        }
        __syncthreads();
        // ---- head GEMM1: y1 = relu(h_t @ W1^T + b1), Ntile = w ----
        v4f ay = (v4f){hb1, hb1, hb1, hb1};
        #pragma unroll
        for (int kk = 0; kk < 2; ++kk) {
            const v8s ah = *(const v8s*)&sh1[pw][kk * 512 + lane * 8];
            ay = mfma(ah, w1f[kk], ay);
        }
        #pragma unroll
        for (int qp = 0; qp < 2; ++qp) {
            unsigned pk = pk2(fmaxf(ay[2 * qp], 0.f), fmaxf(ay[2 * qp + 1], 0.f));
            short* b = &sy1[wsidx + qp * 16];
            b[0] = (short)pk; b[8] = (short)(pk >> 16);
        }
        __syncthreads();
        // ---- head GEMM2 (N=16): wave w==0 only ----
        if (w == 0) {
            v4f a2 = (v4f){hb2, hb2, hb2, hb2};
            #pragma unroll
            for (int kk = 0; kk < 2; ++kk) {
                const v8s a = *(const v8s*)&sy1[kk * 512 + lane * 8];
                a2 = mfma(a, w2f[kk], a2);
            }
            #pragma unroll
            for (int q = 0; q < 4; ++q) {
                size_t row = (size_t)(wg * 16 + hi * 4 + q);
                out[row * 384 + s * 16 + lo] = a2[q] + lb[q];
            }
        }
        // sy1 reuse next step is ordered by the two intervening barriers.
    }
}

extern "C" void kernel_launch(void* const* d_in, const int* in_sizes, int n_in,
                              void* d_out, int out_size, void* d_ws, size_t ws_size,
                              hipStream_t stream) {
    seq2seq<<<dim3(1024), dim3(256), 0, stream>>>(
        (const float*)d_in[0],   // X
        (const float*)d_in[1],   // bias   (d_in[2] = X_mask, unused by reference)
        (const float*)d_in[3],  (const float*)d_in[4],  (const float*)d_in[5],
        (const float*)d_in[6],  (const float*)d_in[7],  (const float*)d_in[8],
        (const float*)d_in[9],  (const float*)d_in[10], (const float*)d_in[11],
        (const float*)d_in[12], (const float*)d_in[13], (const float*)d_in[14],
        (const float*)d_in[15], (const float*)d_in[16],
        (const float*)d_in[17], (const float*)d_in[18],
        (float*)d_out);
}

// Round 6
// 661.192 us; speedup vs baseline: 2.2651x; 2.2651x over previous
//
#include <hip/hip_runtime.h>

typedef short v8s __attribute__((ext_vector_type(8)));   // 8 x bf16 (4 VGPR)
typedef float v4f __attribute__((ext_vector_type(4)));

__device__ __forceinline__ unsigned short f2bf(float f) {
    unsigned u = __builtin_bit_cast(unsigned, f);
    u += 0x7fffu + ((u >> 16) & 1u);               // RNE
    return (unsigned short)(u >> 16);
}
__device__ __forceinline__ float sigm(float x) {
    float e = __builtin_amdgcn_exp2f(-1.44269504f * x);
    return __builtin_amdgcn_rcpf(1.0f + e);
}
__device__ __forceinline__ float tanh_(float x) {
    float e = __builtin_amdgcn_exp2f(2.88539008f * x);
    return 1.0f - 2.0f * __builtin_amdgcn_rcpf(1.0f + e);
}
__device__ __forceinline__ v4f mfma(v8s a, v8s b, v4f c) {
    return __builtin_amdgcn_mfma_f32_16x16x32_bf16(a, b, c, 0, 0, 0);
}
// B-frag for Z = Xin @ W^T from f32 W: lane holds W[n][k0..k0+7] as bf16.
__device__ __forceinline__ v8s ldwf(const float* W, int rowElems, int n, int k0) {
    const float* p = W + (size_t)n * rowElems + k0;
    v8s r;
    #pragma unroll
    for (int j = 0; j < 8; ++j) r[j] = (short)f2bf(p[j]);
    return r;
}

// 512 blocks x 512 threads (8 waves). Block owns 32 batch rows (2 M-tiles).
// Wave w owns z-cols [32w,32w+32) -> weights/wave: enc 56, dec 72 VGPRs, so the
// whole wave state fits the 128-reg budget of 4 waves/SIMD (R5 spilled at 144).
// Gates are reunited per-cell through a 32 KB LDS z-buffer (f32, XOR-swizzled).
__global__ __launch_bounds__(512, 4) void seq2seq(
    const float* __restrict__ X,
    const float* __restrict__ bias,
    const float* __restrict__ eWih0, const float* __restrict__ eWhh0, const float* __restrict__ eb0,
    const float* __restrict__ eWih1, const float* __restrict__ eWhh1, const float* __restrict__ eb1,
    const float* __restrict__ dWih0, const float* __restrict__ dWhh0, const float* __restrict__ db0,
    const float* __restrict__ dWih1, const float* __restrict__ dWhh1, const float* __restrict__ db1,
    const float* __restrict__ rW1, const float* __restrict__ rb1,
    const float* __restrict__ rW2, const float* __restrict__ rb2,
    float* __restrict__ out)
{
    // z exchange: phys(col,row) = col*32 + (row ^ (4*(col&7))), f32. 32 KB.
    __shared__ __align__(16) float zb[8192];
    // h staging, frag-linear per parity: (m,u) -> (m>>4)*1024+(u>>5)*512+((u>>3)&3)*128+(m&15)*8+(u&7)
    __shared__ __align__(16) short sh0[2][2048];
    __shared__ __align__(16) short sh1[2][2048];
    __shared__ __align__(16) short sy1[2048];
    // x tile staging (bf16, A-frag-linear), double-buffered
    __shared__ __align__(16) short sx[2][512];

    const int tid = threadIdx.x;
    const int l   = tid & 63;
    const int w   = tid >> 6;            // wave 0..7: z-cols [32w, 32w+32)
    const int lo  = l & 15, hi = l >> 4;
    const int wg  = blockIdx.x;          // rows [32wg, 32wg+32)

    // zero parity-1 h staging (initial h = 0)
    for (int i = tid; i < 1024; i += 512) {
        ((int*)sh0[1])[i] = 0;
        ((int*)sh1[1])[i] = 0;
    }

    // ---- x staging: thread handles element (m = tid>>4, k = tid&15) ----
    const int sxm = tid >> 4, sxk = tid & 15;
    const int sxw = (sxm >> 4) * 256 + (sxk >> 3) * 128 + (sxm & 15) * 8 + (sxk & 7);
    const float* xp = X + (size_t)(wg * 32 + sxm) * 1536 + sxk;
    sx[0][sxw] = (short)f2bf(xp[0]);      // t = 0

    // GEMM-side z write addresses [c][mt]
    int zwb[2][2];
    #pragma unroll
    for (int c = 0; c < 2; ++c)
        #pragma unroll
        for (int mt = 0; mt < 2; ++mt)
            zwb[c][mt] = ((2 * w + c) * 16 + lo) * 32 + ((mt * 16 + hi * 4) ^ (4 * (lo & 7)));
    // act-side: thread owns cell (u = l, rows 4w..4w+3)
    const int zrb    = l * 32 + ((4 * w) ^ (4 * (l & 7)));
    const int hwbase = (w >> 2) * 1024 + (l >> 5) * 512 + ((l >> 3) & 3) * 128 + 32 * (w & 3) + (l & 7);

    // ---- encoder weights -> register B-frags ----
    v8s wx[2], wA[2][2], wB[2][2], wC[2][2], wD[2][2];
    float bz0[2], bz1[2];
    #pragma unroll
    for (int c = 0; c < 2; ++c) {
        const int n = (2 * w + c) * 16 + lo;
        v8s z8 = {0, 0, 0, 0, 0, 0, 0, 0};
        wx[c] = (hi < 2) ? ldwf(eWih0, 16, n, (hi & 1) * 8) : z8;  // K=16, zero-pad
        #pragma unroll
        for (int kk = 0; kk < 2; ++kk) {
            wA[c][kk] = ldwf(eWhh0, 64, n, kk * 32 + hi * 8);
            wB[c][kk] = ldwf(eWih1, 64, n, kk * 32 + hi * 8);
            wC[c][kk] = ldwf(eWhh1, 64, n, kk * 32 + hi * 8);
        }
        bz0[c] = eb0[n];
        bz1[c] = eb1[n];
    }
    float c0[4] = {0.f, 0.f, 0.f, 0.f};
    float c1[4] = {0.f, 0.f, 0.f, 0.f};
    __syncthreads();

    // ================= encoder =================
    for (int t = 0; t < 96; ++t) {
        const int pw = t & 1, pr = pw ^ 1;
        v4f acc[2][2];
        // ---- l0 GEMM: z = x_t@Wih0^T + h0@Whh0^T + b0 ----
        #pragma unroll
        for (int c = 0; c < 2; ++c)
            #pragma unroll
            for (int mt = 0; mt < 2; ++mt)
                acc[c][mt] = (v4f){bz0[c], bz0[c], bz0[c], bz0[c]};
        #pragma unroll
        for (int mt = 0; mt < 2; ++mt) {
            const v8s ax = *(const v8s*)&sx[pw][mt * 256 + (hi & 1) * 128 + lo * 8];
            #pragma unroll
            for (int c = 0; c < 2; ++c) acc[c][mt] = mfma(ax, wx[c], acc[c][mt]);
        }
        #pragma unroll
        for (int kk = 0; kk < 2; ++kk)
            #pragma unroll
            for (int mt = 0; mt < 2; ++mt) {
                const v8s ah = *(const v8s*)&sh0[pr][mt * 1024 + kk * 512 + l * 8];
                #pragma unroll
                for (int c = 0; c < 2; ++c) acc[c][mt] = mfma(ah, wA[c][kk], acc[c][mt]);
            }
        #pragma unroll
        for (int c = 0; c < 2; ++c)
            #pragma unroll
            for (int mt = 0; mt < 2; ++mt)
                *(v4f*)&zb[zwb[c][mt]] = acc[c][mt];
        __syncthreads();
        // ---- act0 (+ stage x(t+1)) ----
        {
            float xv = 0.f;
            if (t < 95) xv = xp[(size_t)(t + 1) * 16];
            const v4f zi = *(const v4f*)&zb[zrb];
            const v4f zf = *(const v4f*)&zb[zrb + 2048];
            const v4f zg = *(const v4f*)&zb[zrb + 4096];
            const v4f zo = *(const v4f*)&zb[zrb + 6144];
            #pragma unroll
            for (int j = 0; j < 4; ++j) {
                float cc = sigm(zf[j]) * c0[j] + sigm(zi[j]) * tanh_(zg[j]);
                c0[j] = cc;
                sh0[pw][hwbase + 8 * j] = (short)f2bf(sigm(zo[j]) * tanh_(cc));
            }
            if (t < 95) sx[pr][sxw] = (short)f2bf(xv);
        }
        __syncthreads();
        // ---- l1 GEMM: z = h0@Wih1^T + h1@Whh1^T + b1 ----
        #pragma unroll
        for (int c = 0; c < 2; ++c)
            #pragma unroll
            for (int mt = 0; mt < 2; ++mt)
                acc[c][mt] = (v4f){bz1[c], bz1[c], bz1[c], bz1[c]};
        #pragma unroll
        for (int kk = 0; kk < 2; ++kk)
            #pragma unroll
            for (int mt = 0; mt < 2; ++mt) {
                const v8s ah = *(const v8s*)&sh0[pw][mt * 1024 + kk * 512 + l * 8];
                const v8s bh = *(const v8s*)&sh1[pr][mt * 1024 + kk * 512 + l * 8];
                #pragma unroll
                for (int c = 0; c < 2; ++c) {
                    acc[c][mt] = mfma(ah, wB[c][kk], acc[c][mt]);
                    acc[c][mt] = mfma(bh, wC[c][kk], acc[c][mt]);
                }
            }
        #pragma unroll
        for (int c = 0; c < 2; ++c)
            #pragma unroll
            for (int mt = 0; mt < 2; ++mt)
                *(v4f*)&zb[zwb[c][mt]] = acc[c][mt];
        __syncthreads();
        // ---- act1 ----
        {
            const v4f zi = *(const v4f*)&zb[zrb];
            const v4f zf = *(const v4f*)&zb[zrb + 2048];
            const v4f zg = *(const v4f*)&zb[zrb + 4096];
            const v4f zo = *(const v4f*)&zb[zrb + 6144];
            #pragma unroll
            for (int j = 0; j < 4; ++j) {
                float cc = sigm(zf[j]) * c1[j] + sigm(zi[j]) * tanh_(zg[j]);
                c1[j] = cc;
                sh1[pw][hwbase + 8 * j] = (short)f2bf(sigm(zo[j]) * tanh_(cc));
            }
        }
        __syncthreads();
    }
    // finals (t=95, pw=1): h0 in sh0[1], h1 in sh1[1]

    // ---- decoder + head weights ----
    #pragma unroll
    for (int c = 0; c < 2; ++c) {
        const int n = (2 * w + c) * 16 + lo;
        #pragma unroll
        for (int kk = 0; kk < 2; ++kk) {
            wA[c][kk] = ldwf(dWih0, 64, n, kk * 32 + hi * 8);
            wB[c][kk] = ldwf(dWhh0, 64, n, kk * 32 + hi * 8);
            wC[c][kk] = ldwf(dWih1, 64, n, kk * 32 + hi * 8);
            wD[c][kk] = ldwf(dWhh1, 64, n, kk * 32 + hi * 8);
        }
        bz0[c] = db0[n];
        bz1[c] = db1[n];
    }
    const int ct1 = w & 3, mt1 = w >> 2;           // head1 job: y1-tile (mt1, ct1)
    v8s w1f[2];
    #pragma unroll
    for (int kk = 0; kk < 2; ++kk)
        w1f[kk] = ldwf(rW1, 64, ct1 * 16 + lo, kk * 32 + hi * 8);
    const float hb1 = rb1[ct1 * 16 + lo];
    const int wsy = mt1 * 1024 + (ct1 >> 1) * 512 + ((2 * ct1 + (lo >> 3)) & 3) * 128 + hi * 32 + (lo & 7);
    #pragma unroll
    for (int j = 0; j < 4; ++j) { c0[j] = 0.f; c1[j] = 0.f; }

    // ================= decoder =================
    for (int s = 0; s < 24; ++s) {
        const int pw = s & 1, pr = pw ^ 1;   // s=0 reads parity 1 = encoder finals
        v4f acc[2][2];
        // ---- dec l0: z = h_t@dWih0^T + dh0@dWhh0^T + b ----
        #pragma unroll
        for (int c = 0; c < 2; ++c)
            #pragma unroll
            for (int mt = 0; mt < 2; ++mt)
                acc[c][mt] = (v4f){bz0[c], bz0[c], bz0[c], bz0[c]};
        #pragma unroll
        for (int kk = 0; kk < 2; ++kk)
            #pragma unroll
            for (int mt = 0; mt < 2; ++mt) {
                const v8s ah = *(const v8s*)&sh1[pr][mt * 1024 + kk * 512 + l * 8];
                const v8s bh = *(const v8s*)&sh0[pr][mt * 1024 + kk * 512 + l * 8];
                #pragma unroll
                for (int c = 0; c < 2; ++c) {
                    acc[c][mt] = mfma(ah, wA[c][kk], acc[c][mt]);
                    acc[c][mt] = mfma(bh, wB[c][kk], acc[c][mt]);
                }
            }
        #pragma unroll
        for (int c = 0; c < 2; ++c)
            #pragma unroll
            for (int mt = 0; mt < 2; ++mt)
                *(v4f*)&zb[zwb[c][mt]] = acc[c][mt];
        __syncthreads();
        // ---- act0 -> sh0[pw] ----
        {
            const v4f zi = *(const v4f*)&zb[zrb];
            const v4f zf = *(const v4f*)&zb[zrb + 2048];
            const v4f zg = *(const v4f*)&zb[zrb + 4096];
            const v4f zo = *(const v4f*)&zb[zrb + 6144];
            #pragma unroll
            for (int j = 0; j < 4; ++j) {
                float cc = sigm(zf[j]) * c0[j] + sigm(zi[j]) * tanh_(zg[j]);
                c0[j] = cc;
                sh0[pw][hwbase + 8 * j] = (short)f2bf(sigm(zo[j]) * tanh_(cc));
            }
        }
        __syncthreads();
        // ---- dec l1: z = h0new@dWih1^T + dh1@dWhh1^T + b ----
        #pragma unroll
        for (int c = 0; c < 2; ++c)
            #pragma unroll
            for (int mt = 0; mt < 2; ++mt)
                acc[c][mt] = (v4f){bz1[c], bz1[c], bz1[c], bz1[c]};
        #pragma unroll
        for (int kk = 0; kk < 2; ++kk)
            #pragma unroll
            for (int mt = 0; mt < 2; ++mt) {
                const v8s ah = *(const v8s*)&sh0[pw][mt * 1024 + kk * 512 + l * 8];
                const v8s bh = *(const v8s*)&sh1[pr][mt * 1024 + kk * 512 + l * 8];
                #pragma unroll
                for (int c = 0; c < 2; ++c) {
                    acc[c][mt] = mfma(ah, wC[c][kk], acc[c][mt]);
                    acc[c][mt] = mfma(bh, wD[c][kk], acc[c][mt]);
                }
            }
        #pragma unroll
        for (int c = 0; c < 2; ++c)
            #pragma unroll
            for (int mt = 0; mt < 2; ++mt)
                *(v4f*)&zb[zwb[c][mt]] = acc[c][mt];
        __syncthreads();
        // ---- act1 -> sh1[pw] ----
        {
            const v4f zi = *(const v4f*)&zb[zrb];
            const v4f zf = *(const v4f*)&zb[zrb + 2048];
            const v4f zg = *(const v4f*)&zb[zrb + 4096];
            const v4f zo = *(const v4f*)&zb[zrb + 6144];
            #pragma unroll
            for (int j = 0; j < 4; ++j) {
                float cc = sigm(zf[j]) * c1[j] + sigm(zi[j]) * tanh_(zg[j]);
                c1[j] = cc;
                sh1[pw][hwbase + 8 * j] = (short)f2bf(sigm(zo[j]) * tanh_(cc));
            }
        }
        __syncthreads();
        // ---- head GEMM1: y1 = relu(h_t@W1^T + b1); wave job (mt1, ct1) ----
        {
            v4f ay = (v4f){hb1, hb1, hb1, hb1};
            #pragma unroll
            for (int kk = 0; kk < 2; ++kk) {
                const v8s ah = *(const v8s*)&sh1[pw][mt1 * 1024 + kk * 512 + l * 8];
                ay = mfma(ah, w1f[kk], ay);
            }
            #pragma unroll
            for (int q = 0; q < 4; ++q)
                sy1[wsy + 8 * q] = (short)f2bf(fmaxf(ay[q], 0.f));
        }
        __syncthreads();
        // ---- head GEMM2 (N=16): waves 0 (mt 0) and 4 (mt 1) ----
        if (ct1 == 0) {
            const v8s w2a = ldwf(rW2, 64, lo, hi * 8);
            const v8s w2b = ldwf(rW2, 64, lo, 32 + hi * 8);
            const float hb2 = rb2[lo];
            v4f a2 = (v4f){hb2, hb2, hb2, hb2};
            a2 = mfma(*(const v8s*)&sy1[mt1 * 1024 + l * 8], w2a, a2);
            a2 = mfma(*(const v8s*)&sy1[mt1 * 1024 + 512 + l * 8], w2b, a2);
            #pragma unroll
            for (int q = 0; q < 4; ++q) {
                size_t row = (size_t)(wg * 32 + mt1 * 16 + hi * 4 + q);
                out[row * 384 + s * 16 + lo] = a2[q] + bias[row * 16 + lo];
            }
        }
        // sy1 next written only after 4 barriers (head1 of s+1) — safe.
    }
}

extern "C" void kernel_launch(void* const* d_in, const int* in_sizes, int n_in,
                              void* d_out, int out_size, void* d_ws, size_t ws_size,
                              hipStream_t stream) {
    seq2seq<<<dim3(512), dim3(512), 0, stream>>>(
        (const float*)d_in[0],   // X
        (const float*)d_in[1],   // bias   (d_in[2] = X_mask, unused by reference)
        (const float*)d_in[3],  (const float*)d_in[4],  (const float*)d_in[5],
        (const float*)d_in[6],  (const float*)d_in[7],  (const float*)d_in[8],
        (const float*)d_in[9],  (const float*)d_in[10], (const float*)d_in[11],
        (const float*)d_in[12], (const float*)d_in[13], (const float*)d_in[14],
        (const float*)d_in[15], (const float*)d_in[16],
        (const float*)d_in[17], (const float*)d_in[18],
        (float*)d_out);
}